// Round 5
// baseline (131.607 us; speedup 1.0000x reference)
//
#include <hip/hip_runtime.h>
#include <stdint.h>

// Problem constants
#define BATCH 4096
#define DIN   512
#define NT    64      // trees
#define NL    64      // leaves
#define LD    128     // leaf dims

typedef __attribute__((ext_vector_type(8))) short bf16x8;
typedef __attribute__((ext_vector_type(8))) _Float16 f16x8;
typedef __attribute__((ext_vector_type(4))) float f32x4;

typedef const __attribute__((address_space(1))) unsigned char* gcp_t;
typedef __attribute__((address_space(3))) unsigned char* lp_t;

__device__ __forceinline__ void gl_lds16(const void* g, void* l) {
  __builtin_amdgcn_global_load_lds((gcp_t)g, (lp_t)l, 16, 0, 0);
}

// packed 2xf32 -> 2xbf16 (round-half-up) in 3 VALU: 2 adds + 1 v_perm
__device__ __forceinline__ unsigned pk_bf16(float a, float b) {
  union { float f; unsigned u; } ua, ub;
  ua.f = a; ub.f = b;
  return __builtin_amdgcn_perm(ub.u + 0x8000u, ua.u + 0x8000u, 0x07060302u);
}

// ---------------- merged prep kernel (round-0 measured-best, unchanged) --------
__global__ __launch_bounds__(256) void prep_all_k(
    const float* __restrict__ x, const float* __restrict__ W,
    const float* __restrict__ gates, const float* __restrict__ lw,
    unsigned short* __restrict__ xb, unsigned short* __restrict__ Wt,
    unsigned short* __restrict__ Wv2, float* __restrict__ out) {
  __shared__ float smem[12288];   // 48 KB
  const int bx = blockIdx.x;
  const int tid = threadIdx.x;

  if (bx < 2048) {
    int i = bx * 256 + tid;
    float4 v = ((const float4*)x)[i];
    uint2 o;
    o.x = pk_bf16(v.x, v.y);
    o.y = pk_bf16(v.z, v.w);
    ((uint2*)xb)[i] = o;
  } else if (bx < 2304) {
    int bb = bx - 2048;
    int n = bb >> 2, d0 = (bb & 3) * 128;
    float* buf = smem;   // [d_local][t], 128*64 floats = 32 KB
    if (n < 63) {
      for (int it = 0; it < 32; ++it) {
        int idx = it * 256 + tid;   // idx = d_local*64 + t
        buf[idx] = W[n * 32768 + (d0 + (idx >> 6)) * 64 + (idx & 63)];
      }
    }
    __syncthreads();
    int t = tid >> 2, q = tid & 3;
    unsigned vals[16];
    #pragma unroll
    for (int j = 0; j < 16; ++j) {
      float va = (n < 63) ? buf[(q * 32 + 2 * j) * 64 + t] : 0.0f;
      float vb = (n < 63) ? buf[(q * 32 + 2 * j + 1) * 64 + t] : 0.0f;
      vals[j] = (n < 63) ? pk_bf16(va, vb) : 0u;
    }
    uint4* dst = (uint4*)(Wt + t * 32768 + n * 512 + d0 + q * 32);
    const uint4* src = (const uint4*)vals;
    dst[0] = src[0]; dst[1] = src[1]; dst[2] = src[2]; dst[3] = src[3];
  } else if (bx < 2432) {
    int d = bx - 2304;           // 0..127
    float* gb = smem;            // [l*64 + t]
    float* lb = smem + 4096;
    float* wv = smem + 8192;
    for (int it = 0; it < 16; ++it) {
      int idx = it * 256 + tid;  // l*64 + t
      int l = idx >> 6;
      int ga = l * 8192 + d * 64 + (idx & 63);
      gb[idx] = gates[ga];
      lb[idx] = lw[ga];
    }
    __syncthreads();
    int wave = tid >> 6, lane = tid & 63;
    for (int l = wave; l < 64; l += 4) {
      float v = gb[l * 64 + lane];
      float mx = v;
      for (int m = 32; m >= 1; m >>= 1) mx = fmaxf(mx, __shfl_xor(mx, m));
      float e = __expf(v - mx);
      float s = e;
      for (int m = 32; m >= 1; m >>= 1) s += __shfl_xor(s, m);
      wv[l * 64 + lane] = lb[l * 64 + lane] * e / s;
    }
    __syncthreads();
    #pragma unroll
    for (int c = 0; c < 2; ++c) {
      int k0 = tid * 16 + c * 8;
      unsigned o[4];
      #pragma unroll
      for (int j = 0; j < 4; ++j) {
        int ka = k0 + 2 * j, kb = k0 + 2 * j + 1;   // kappa = t*64 + l
        o[j] = pk_bf16(wv[(ka & 63) * 64 + (ka >> 6)], wv[(kb & 63) * 64 + (kb >> 6)]);
      }
      *(uint4*)(Wv2 + (long)d * 4096 + k0) = *(const uint4*)o;
    }
  } else {
    float4 z = {0.f, 0.f, 0.f, 0.f};
    int base = (bx - 2432) * 256 + tid;
    float4* o4 = (float4*)out;
    #pragma unroll
    for (int k = 0; k < 16; ++k)
      o4[k * 8192 + base] = z;
  }
}

// ---- FUSED GEMM1 + tree product + GEMM2: x->logits->sigmoid->leafP->out ------
// R14: eliminate the 32MB P round-trip + gemm2 launch. Retile to 128 rows x
// 4 trees (256 node-cols) so each block holds K=256 of the second GEMM ->
// atomic contributions drop to 16/element (8.4M total, vs 32/elem at the old
// 2-tree tile). Main loop is the EXACT round-0 pipeline mirrored (72 KB LDS,
// 2 blocks/CU, tri-buffer dist-2, ONE barrier/iter, 3 gl_lds/thread, vmcnt(3)).
// Epilogue: sigmoid -> gbuf f16[128][256] (32-chunk XOR swizzle) -> tree
// product per (row,tree) thread -> leaf P bf16 into LDS (staging-layout
// subtiles, same XOR slot swizzle as main loop so the proven frag reader
// applies) -> in-block GEMM M128 K256 N128 (A from LDS, B=Wv2 from global,
// L2-hot) -> one atomicAdd per out element.
__global__ __launch_bounds__(512, 4) void gemm1_fused_k(
    const unsigned short* __restrict__ xb,   // [4096][512] bf16
    const unsigned short* __restrict__ Wt,   // [64][64][512] bf16 (row = t*64+n)
    const float* __restrict__ bias,          // [63][64]
    const unsigned short* __restrict__ Wv2,  // [128][4096] bf16, kappa = t*64+l
    float* __restrict__ out)                 // [4096][128] f32, pre-zeroed
{
  __shared__ __align__(16) char smem[73728];              // 72 KB
  unsigned short* AsB = (unsigned short*)smem;            // 3 x 4096 shorts (24 KB)
  unsigned short* BsB = (unsigned short*)(smem + 24576);  // 3 x 8192 shorts (48 KB)
  _Float16* gbuf = (_Float16*)smem;                       // [128][256] f16 (64 KB overlay)
  unsigned short* plds = (unsigned short*)smem;           // 8 x [128][32] bf16 (64 KB overlay)

  const int tid = threadIdx.x;
  const int wave = tid >> 6, lane = tid & 63;

  // bijective XCD remap: 512 wg = 8 xcd x 64; per XCD 8 b0 x 8 tq (A 1MB + B 2MB in L2)
  const int lin = blockIdx.x;
  const int xcd = lin & 7, idx = lin >> 3;
  const int bt = (xcd >> 1) * 8 + (idx >> 3);   // 0..31 batch tile (128 rows)
  const int tq = (xcd & 1) * 8 + (idx & 7);     // 0..15 tree quad
  const int b0 = bt << 7;
  const int n0 = tq << 8;                       // Wt row base (t*64+n)

  const int wm = (wave >> 2) << 6;   // 0 / 64
  const int wn = (wave & 3) << 6;    // 0,64,128,192
  const int mrow = lane & 15, kg = lane >> 4;
  const int slot = (kg ^ ((mrow >> 1) & 3)) * 8;   // staging reader slot

  // bias: col = wn + j*16 + mrow -> tree = wave&3, node = j*16+mrow
  float bv[4];
  #pragma unroll
  for (int j = 0; j < 4; ++j) {
    int node = j * 16 + mrow;
    bv[j] = (node < 63) ? bias[node * 64 + tq * 4 + (wave & 3)] : 0.0f;
  }

  const f32x4 zero = {0.f, 0.f, 0.f, 0.f};
  f32x4 acc[4][4];
  #pragma unroll
  for (int i = 0; i < 4; ++i)
    #pragma unroll
    for (int j = 0; j < 4; ++j) acc[i][j] = zero;

  // A granules: 512 (128 rows x 4 chunks) -> 1/thread. B: 1024 -> 2/thread.
  const int cA = ((tid & 3) ^ ((tid >> 3) & 3)) * 8;    // pre-swizzled source chunk
  const unsigned short* Ag0 = xb + (long)(b0 + (tid >> 2)) * 512 + cA;
  const unsigned short* Bg0 = Wt + (long)(n0 + (tid >> 2)) * 512 + cA;
  const unsigned short* Bg1 = Wt + (long)(n0 + 128 + (tid >> 2)) * 512 + cA;
  const int ldst = tid * 8;             // linear LDS short-offset (wave-uniform base)

  // preload tile 0 -> buf 0, tile 1 -> buf 1 (3 loads each)
  gl_lds16(Ag0, AsB + ldst);
  gl_lds16(Bg0, BsB + ldst);
  gl_lds16(Bg1, BsB + ldst + 4096);
  gl_lds16(Ag0 + 32, AsB + 4096 + ldst);
  gl_lds16(Bg0 + 32, BsB + 8192 + ldst);
  gl_lds16(Bg1 + 32, BsB + 8192 + ldst + 4096);

  for (int it = 0; it < 16; ++it) {
    const int bufA = (it % 3) * 4096;
    const int bufB = (it % 3) * 8192;
    // <=6 loads outstanding; oldest 3 are tile `it`: vmcnt(3) completes it.
    // lgkmcnt(0) drains prev iter's ds_reads BEFORE the barrier (race fix).
    if (it < 15) {
      asm volatile("s_waitcnt vmcnt(3) lgkmcnt(0)" ::: "memory");
    } else {
      asm volatile("s_waitcnt vmcnt(0) lgkmcnt(0)" ::: "memory");
    }
    asm volatile("s_barrier" ::: "memory");   // tile it staged; buf (it+2)%3's readers drained

    if (it < 14) {                            // prefetch tile it+2 (post-barrier: safe)
      const int kk = (it + 2) * 32;
      const int nA = ((it + 2) % 3) * 4096;
      const int nB = ((it + 2) % 3) * 8192;
      gl_lds16(Ag0 + kk, AsB + nA + ldst);
      gl_lds16(Bg0 + kk, BsB + nB + ldst);
      gl_lds16(Bg1 + kk, BsB + nB + ldst + 4096);
    }

    bf16x8 fa[4], fb[4];
    #pragma unroll
    for (int i = 0; i < 4; ++i)
      fa[i] = *(const bf16x8*)(AsB + bufA + (wm + i * 16 + mrow) * 32 + slot);
    #pragma unroll
    for (int j = 0; j < 4; ++j)
      fb[j] = *(const bf16x8*)(BsB + bufB + (wn + j * 16 + mrow) * 32 + slot);
    #pragma unroll
    for (int i = 0; i < 4; ++i)
      #pragma unroll
      for (int j = 0; j < 4; ++j)
        acc[i][j] = __builtin_amdgcn_mfma_f32_16x16x32_bf16(fa[i], fb[j], acc[i][j], 0, 0, 0);
  }

  __syncthreads();   // full drain + barrier before gbuf overlays the staging buffers

  // epilogue 1: bias + sigmoid -> gbuf f16[128][256], 32-chunk XOR swizzle.
  #pragma unroll
  for (int i = 0; i < 4; ++i)
    #pragma unroll
    for (int j = 0; j < 4; ++j) {
      int col = wn + j * 16 + mrow;        // 0..255 = tree*64 + node
      int ch = col >> 3, sub = col & 7;
      #pragma unroll
      for (int r = 0; r < 4; ++r) {
        int row = wm + i * 16 + kg * 4 + r;    // [0,128)
        float z = acc[i][j][r] + bv[j];
        gbuf[row * 256 + (((ch ^ (row & 31)) << 3) | sub)] =
            (_Float16)__builtin_amdgcn_rcpf(1.0f + __expf(-z));
      }
    }
  __syncthreads();

  // epilogue 2: tree product. 512 threads = 128 rows x 4 trees.
  {
    const int row = tid >> 2, tree = tid & 3;
    const int rx = row & 31;
    float g[63];
    #pragma unroll
    for (int c = 0; c < 8; ++c) {
      f16x8 gv = *(const f16x8*)(gbuf + row * 256 + (((tree * 8 + c) ^ rx) << 3));
      #pragma unroll
      for (int j = 0; j < 8; ++j) {
        int n = c * 8 + j;
        if (n < 63) g[n] = (float)gv[j];
      }
    }
    float P3[8];
    {
      float a0 = g[0],            a1 = 1.0f - g[0];
      float c0_ = a0 * g[1],      c1_ = a0 * (1.0f - g[1]);
      float c2_ = a1 * g[2],      c3_ = a1 * (1.0f - g[2]);
      P3[0] = c0_ * g[3];  P3[1] = c0_ * (1.0f - g[3]);
      P3[2] = c1_ * g[4];  P3[3] = c1_ * (1.0f - g[4]);
      P3[4] = c2_ * g[5];  P3[5] = c2_ * (1.0f - g[5]);
      P3[6] = c3_ * g[6];  P3[7] = c3_ * (1.0f - g[6]);
    }
    unsigned pk32[32];                       // 64 leaf bf16, packed
    #pragma unroll
    for (int o = 0; o < 8; ++o) {
      float g3 = g[7 + o];
      float q0 = P3[o] * g3, q1 = P3[o] * (1.0f - g3);
      float g4a = g[15 + 2 * o], g4b = g[16 + 2 * o];
      float r0 = q0 * g4a, r1 = q0 * (1.0f - g4a);
      float r2 = q1 * g4b, r3 = q1 * (1.0f - g4b);
      #pragma unroll
      for (int h = 0; h < 4; ++h) {
        float g5 = g[31 + 4 * o + h];
        float rr2 = (h == 0) ? r0 : (h == 1) ? r1 : (h == 2) ? r2 : r3;
        pk32[o * 4 + h] = pk_bf16(rr2 * g5, rr2 * (1.0f - g5));
      }
    }
    __syncthreads();   // all g-reads done before leaf-P overwrites gbuf region

    // leaf P -> LDS, staging-compatible layout: subtile ksub = kappa>>5 is
    // [128 rows][32 kappa] with slot swizzle (c ^ ((row>>1)&3)) matching the
    // main-loop frag reader. kappa = tree*64 + leaf.
    #pragma unroll
    for (int g2 = 0; g2 < 8; ++g2) {
      int ksub = tree * 2 + (g2 >> 2);
      int c = g2 & 3;
      uint4 v = {pk32[g2 * 4], pk32[g2 * 4 + 1], pk32[g2 * 4 + 2], pk32[g2 * 4 + 3]};
      *(uint4*)(plds + ksub * 4096 + row * 32 + ((c ^ ((row >> 1) & 3)) << 3)) = v;
    }
  }
  __syncthreads();

  // epilogue 3: in-block GEMM  out[128 rows][128 d] += P(128x256) * Wv2^T.
  // 8 waves 2Mx4N: per-wave 64 rows x 32 d; K=256 in 8 subtiles.
  {
    const int wm2 = (wave >> 2) << 6;      // 0 / 64
    const int wn2 = (wave & 3) << 5;       // 0,32,64,96
    f32x4 acc2[4][2];
    #pragma unroll
    for (int i = 0; i < 4; ++i)
      #pragma unroll
      for (int j = 0; j < 2; ++j) acc2[i][j] = zero;

    #pragma unroll
    for (int kq = 0; kq < 8; ++kq) {
      bf16x8 fa2[4], fbg[2];
      #pragma unroll
      for (int j = 0; j < 2; ++j)
        fbg[j] = *(const bf16x8*)(Wv2 + (long)(wn2 + j * 16 + mrow) * 4096 +
                                  tq * 256 + kq * 32 + kg * 8);
      #pragma unroll
      for (int i = 0; i < 4; ++i)
        fa2[i] = *(const bf16x8*)(plds + kq * 4096 + (wm2 + i * 16 + mrow) * 32 + slot);
      #pragma unroll
      for (int i = 0; i < 4; ++i)
        #pragma unroll
        for (int j = 0; j < 2; ++j)
          acc2[i][j] = __builtin_amdgcn_mfma_f32_16x16x32_bf16(fa2[i], fbg[j], acc2[i][j], 0, 0, 0);
    }

    #pragma unroll
    for (int i = 0; i < 4; ++i)
      #pragma unroll
      for (int j = 0; j < 2; ++j) {
        int col = wn2 + j * 16 + mrow;
        #pragma unroll
        for (int r = 0; r < 4; ++r) {
          int row = wm2 + i * 16 + kg * 4 + r;
          atomicAdd(&out[(long)(b0 + row) * 128 + col], acc2[i][j][r]);
        }
      }
  }
}

extern "C" void kernel_launch(void* const* d_in, const int* in_sizes, int n_in,
                              void* d_out, int out_size, void* d_ws, size_t ws_size,
                              hipStream_t stream) {
  const float* x     = (const float*)d_in[0];
  const float* W     = (const float*)d_in[1];
  const float* b     = (const float*)d_in[2];
  const float* lw    = (const float*)d_in[3];
  const float* gates = (const float*)d_in[4];
  float* out = (float*)d_out;

  char* ws = (char*)d_ws;
  unsigned short* xb  = (unsigned short*)(ws);                    // 4 MB
  unsigned short* Wt  = (unsigned short*)(ws + (4l  << 20));      // 4 MB
  unsigned short* Wv2 = (unsigned short*)(ws + (8l  << 20));      // 1 MB

  hipLaunchKernelGGL(prep_all_k,    dim3(2464), dim3(256), 0, stream,
                     x, W, gates, lw, xb, Wt, Wv2, out);
  hipLaunchKernelGGL(gemm1_fused_k, dim3(512),  dim3(512), 0, stream,
                     xb, Wt, b, Wv2, out);
}